// Round 11
// baseline (332.010 us; speedup 1.0000x reference)
//
#include <hip/hip_runtime.h>
#include <hip/hip_bf16.h>

typedef __bf16 bf16;
typedef __bf16 bf16x8 __attribute__((ext_vector_type(8)));
typedef __bf16 bf16x4 __attribute__((ext_vector_type(4)));
typedef __bf16 bf16x2 __attribute__((ext_vector_type(2)));
typedef float f32x4 __attribute__((ext_vector_type(4)));

static __device__ __forceinline__ f32x4 mfma16(bf16x8 a, bf16x8 b, f32x4 c) {
    return __builtin_amdgcn_mfma_f32_16x16x32_bf16(a, b, c, 0, 0, 0);
}

static __device__ __forceinline__ void load16_to_lds(const void* g, void* l) {
    __builtin_amdgcn_global_load_lds(
        (const __attribute__((address_space(1))) unsigned int*)g,
        (__attribute__((address_space(3))) unsigned int*)l, 16, 0, 0);
}

#define LKV 2048
#define DM 256

// ================= shared GEMM body: Y[64 x 256] = X * W^T, W read as f32 =================
template<bool IN_BF16, bool OUT_BF16, bool HAS_BIAS>
static __device__ __forceinline__ void gemm_body(char* smem,
                                                 const void* __restrict__ Xv,
                                                 const float* __restrict__ Wf,
                                                 const float* __restrict__ bias,
                                                 float scale, void* __restrict__ Y,
                                                 long rowbase) {
    bf16* Xl  = (bf16*)smem;            // [64][264] bf16 (528B rows)
    char* WlB = smem + 33792;           // [256][40] bf16 (80B rows)
    const int tid  = threadIdx.x;
    const int lane = tid & 63, wave = tid >> 6;
    const int hi = lane >> 4, lo = lane & 15;

    if (IN_BF16) {
        const bf16* Xb = (const bf16*)Xv;
#pragma unroll
        for (int i = 0; i < 8; ++i) {
            int idx = i * 256 + tid;
            int r = idx >> 5, c8 = (idx & 31) * 8;
            uint4 v = *(const uint4*)(Xb + (rowbase + r) * 256 + c8);
            *(uint4*)(Xl + r * 264 + c8) = v;
        }
    } else {
        const float* X = (const float*)Xv;
#pragma unroll
        for (int i = 0; i < 16; ++i) {
            int idx4 = i * 256 + tid;
            int e = idx4 * 4;
            int r = e >> 8, c = e & 255;
            float4 v = *(const float4*)(X + (rowbase + r) * 256 + c);
            bf16x4 o;
            o[0] = (bf16)v.x; o[1] = (bf16)v.y; o[2] = (bf16)v.z; o[3] = (bf16)v.w;
            *(bf16x4*)(Xl + r * 264 + c) = o;
        }
    }

    f32x4 acc[16];
    const f32x4 zero = {0.f, 0.f, 0.f, 0.f};
#pragma unroll
    for (int n = 0; n < 16; ++n) acc[n] = zero;

    for (int ks = 0; ks < 8; ++ks) {
        __syncthreads();
#pragma unroll
        for (int c = 0; c < 8; ++c) {
            int idx = c * 256 + tid;            // 2048 float4 chunks
            int e = idx >> 3, q4 = (idx & 7) * 4;
            float4 v = *(const float4*)(Wf + e * 256 + ks * 32 + q4);
            bf16x4 o;
            o[0] = (bf16)v.x; o[1] = (bf16)v.y; o[2] = (bf16)v.z; o[3] = (bf16)v.w;
            *(bf16x4*)(WlB + e * 80 + q4 * 2) = o;
        }
        __syncthreads();
        bf16x8 a = *(const bf16x8*)((const char*)Xl + (wave * 16 + lo) * 528 + ks * 64 + hi * 16);
#pragma unroll
        for (int n = 0; n < 16; ++n) {
            bf16x8 bfr = *(const bf16x8*)(WlB + (n * 16 + lo) * 80 + hi * 16);
            acc[n] = mfma16(a, bfr, acc[n]);
        }
    }

#pragma unroll
    for (int n = 0; n < 16; ++n) {
        int col = n * 16 + lo;
        float bv = HAS_BIAS ? bias[col] : 0.f;
#pragma unroll
        for (int r = 0; r < 4; ++r) {
            long row = rowbase + wave * 16 + hi * 4 + r;
            float v = acc[n][r] * scale + bv;
            if (OUT_BF16) ((bf16*)Y)[row * 256 + col] = (bf16)v;
            else          ((float*)Y)[row * 256 + col] = v;
        }
    }
}

// ================= prep_qk: blocks [0,1024) = q/k projection; [1024,3072) = tsp -> tspF ======
// tspF frag layout: byte addr = b*1MB + ((t32*16 + dt)*64 + fl)*16,
// holding tspT[d = dt*16 + (fl&15)][kv = t32*32 + (fl>>4)*8 .. +7] as bf16x8.
__global__ __launch_bounds__(256) void prep_qk(const float* __restrict__ q,
                                               const float* __restrict__ k,
                                               const float* __restrict__ wqk,
                                               const float* __restrict__ tsp,
                                               bf16* __restrict__ qp,
                                               bf16* __restrict__ kp,
                                               bf16* __restrict__ tspF) {
    __shared__ __align__(16) char smem[54272];
    const int tid = threadIdx.x;
    int bid = (int)blockIdx.x;
    if (bid < 1024) {
        bool is_k = bid >= 512;
        // qp scale folds 1/temperature (1/16) AND log2e (exp2-based softmax)
        gemm_body<false, true, false>(smem, is_k ? k : q, wqk, nullptr,
                                      is_k ? 1.0f : 0.09016844f, is_k ? kp : qp,
                                      (long)(bid & 511) * 64);
        return;
    }
    int id = bid - 1024;                       // 2048 tiles: 16 b x 32 kv-tiles x 4 d-tiles
    const int b = id >> 7;
    const int kv0 = (id & 31) * 64, d0 = ((id >> 5) & 3) * 64;
    float (*tile)[65] = (float(*)[65])smem;
#pragma unroll
    for (int i = 0; i < 4; ++i) {
        int idx = i * 256 + tid;
        int kv = idx >> 4, c4 = (idx & 15) * 4;
        float4 v = *(const float4*)(tsp + ((long)(b * LKV + kv0 + kv)) * DM + d0 + c4);
        tile[kv][c4 + 0] = v.x; tile[kv][c4 + 1] = v.y;
        tile[kv][c4 + 2] = v.z; tile[kv][c4 + 3] = v.w;
    }
    __syncthreads();
    char* outb = (char*)tspF + ((long)b << 20);
#pragma unroll
    for (int i = 0; i < 2; ++i) {
        int w = i * 256 + tid;
        int ti = w >> 8;
        int dti = (w >> 6) & 3;
        int fl = w & 63;
        int hi = fl >> 4, lo = fl & 15;
        bf16x8 o;
#pragma unroll
        for (int j = 0; j < 8; ++j) o[j] = (bf16)tile[ti * 32 + hi * 8 + j][dti * 16 + lo];
        int t_abs = (kv0 >> 5) + ti;
        int dt_abs = (d0 >> 4) + dti;
        *(bf16x8*)(outb + (((t_abs * 16 + dt_abs) << 6) + fl) * 16) = o;
    }
}

// ================= flash10: kv-halved blocks, 4 waves, 32KB LDS -> 4 blocks/CU ===============
// grid = 1024 (XCD-swizzled): block = (batch, 64 q-rows, kv-half). 32 phases of kv=32.
// kp double-buffered in LDS (DMA, swizzled); tsp + q fragments streamed from L1 each phase.
// Registers engineered ~<=128 total for 4 waves/SIMD. Partial (o,l,m,tm) written to ws;
// halves merged inside gemm_out_merge.
__global__ __launch_bounds__(256, 4) void flash10(const bf16* __restrict__ qp,
                                                  const bf16* __restrict__ kp,
                                                  const bf16* __restrict__ tspF,
                                                  bf16* __restrict__ oPart,
                                                  float* __restrict__ lmt) {
    __shared__ __align__(16) char kbuf[2][16384];   // [kv][512B], chunk i ^= (kv&7)
    const int tid  = threadIdx.x;
    const int lane = tid & 63, wave = tid >> 6;
    const int hi = lane >> 4, lo = lane & 15;

    int id  = (int)blockIdx.x;
    int bid = (id & 7) * 128 + (id >> 3);      // 8 XCDs x 128 blocks -> 2 batches/XCD
    const int b    = bid >> 6;
    const int qb   = (bid >> 1) & 31;
    const int half = bid & 1;
    const long qbase  = (long)b * LKV + qb * 64;
    const char* kp_g  = (const char*)(kp + (long)b * LKV * DM) + half * 524288;
    const char* tsp_f = (const char*)tspF + ((long)b << 20) + (long)half * 524288 + lane * 16;
    const bf16* qrow  = qp + (qbase + wave * 16 + lo) * DM;   // lane's q-row (q = lo)

    int kp_off[4];
#pragma unroll
    for (int j = 0; j < 4; ++j) {
        int kv = wave * 8 + j * 2 + (lane >> 5);
        kp_off[j] = kv * 512 + (((lane & 31) ^ (kv & 7)) << 4);
    }
    int bp_src[4];
#pragma unroll
    for (int k2 = 0; k2 < 4; ++k2)
        bp_src[k2] = ((((hi & 1) * 2 + (k2 >> 1)) << 4) + lo) << 2;
    const int kswz = (lo & 7) << 4;

    f32x4 o[16];
    const f32x4 zero = {0.f, 0.f, 0.f, 0.f};
#pragma unroll
    for (int n = 0; n < 16; ++n) o[n] = zero;
    float m = -1e30f, tm = -1e30f, l = 0.f;

    // prologue: DMA tile 0 -> slot 0
#pragma unroll
    for (int j = 0; j < 4; ++j)
        load16_to_lds(kp_g + kp_off[j], &kbuf[0][wave * 4096 + j * 1024]);

    for (int t = 0; t < 32; ++t) {
        // own DMA(t) was issued >= a phase ago -> near-free drain; then block-wide barrier
        asm volatile("s_waitcnt vmcnt(0)" ::: "memory");
        __builtin_amdgcn_sched_barrier(0);
        __builtin_amdgcn_s_barrier();
        __builtin_amdgcn_sched_barrier(0);

        // issue DMA(t+1) immediately (into the slot everyone finished reading in t-1)
        if (t < 31) {
            const char* src = kp_g + (long)(t + 1) * 16384;
            char* dst = &kbuf[(t + 1) & 1][wave * 4096];
#pragma unroll
            for (int j = 0; j < 4; ++j)
                load16_to_lds(src + kp_off[j], dst + j * 1024);
        }

        // ---- QK(t): S^T[kv][q]; aq streamed from L1 (qp rows L1-resident) ----
        f32x4 s0 = zero, s1 = zero;
        const char* kb = kbuf[t & 1];
        __builtin_amdgcn_s_setprio(1);
#pragma unroll
        for (int ks = 0; ks < 8; ++ks) {
            bf16x8 aqv = *(const bf16x8*)(qrow + ks * 32 + hi * 8);
            bf16x8 k0 = *(const bf16x8*)(kb + (lo << 9) + ((ks * 64 + hi * 16) ^ kswz));
            bf16x8 k1 = *(const bf16x8*)(kb + ((16 + lo) << 9) + ((ks * 64 + hi * 16) ^ kswz));
            s0 = mfma16(k0, aqv, s0);
            s1 = mfma16(k1, aqv, s1);
        }
        __builtin_amdgcn_s_setprio(0);

        // ---- softmax(t): per-lane for q=lo (exp2 domain) ----
        float pm = fmaxf(fmaxf(fmaxf(s0[0], s0[1]), fmaxf(s0[2], s0[3])),
                         fmaxf(fmaxf(s1[0], s1[1]), fmaxf(s1[2], s1[3])));
        pm = fmaxf(pm, __shfl_xor(pm, 16));
        pm = fmaxf(pm, __shfl_xor(pm, 32));
        tm = fmaxf(tm, pm);
        if (__any(pm > m + 11.5f)) {      // defer-max: 8 nats = 11.5 bits
            float nm = fmaxf(m, pm);
            float a = exp2f(m - nm);
            m = nm;
            l *= a;
#pragma unroll
            for (int n = 0; n < 16; ++n) o[n] *= a;
        }
        float p00 = exp2f(s0[0] - m), p01 = exp2f(s0[1] - m);
        float p02 = exp2f(s0[2] - m), p03 = exp2f(s0[3] - m);
        float p10 = exp2f(s1[0] - m), p11 = exp2f(s1[1] - m);
        float p12 = exp2f(s1[2] - m), p13 = exp2f(s1[3] - m);
        l += (p00 + p01) + (p02 + p03) + (p10 + p11) + (p12 + p13);

        int cvt[2][2];
        {
            bf16x2 pr;
            pr[0] = (bf16)p00; pr[1] = (bf16)p01; cvt[0][0] = __builtin_bit_cast(int, pr);
            pr[0] = (bf16)p02; pr[1] = (bf16)p03; cvt[0][1] = __builtin_bit_cast(int, pr);
            pr[0] = (bf16)p10; pr[1] = (bf16)p11; cvt[1][0] = __builtin_bit_cast(int, pr);
            pr[0] = (bf16)p12; pr[1] = (bf16)p13; cvt[1][1] = __builtin_bit_cast(int, pr);
        }
        int pki[4];
#pragma unroll
        for (int k2 = 0; k2 < 4; ++k2) {
            int a0 = __builtin_amdgcn_ds_bpermute(bp_src[k2], cvt[0][k2 & 1]);
            int a1 = __builtin_amdgcn_ds_bpermute(bp_src[k2], cvt[1][k2 & 1]);
            pki[k2] = (hi < 2) ? a0 : a1;
        }
        int4 pii = make_int4(pki[0], pki[1], pki[2], pki[3]);
        bf16x8 pk = __builtin_bit_cast(bf16x8, pii);   // P[q=lo][kv = 8*hi + j]

        // ---- PV(t): tsp frags streamed 4-deep from L1; register-only MFMAs ----
        const char* ttb = tsp_f + (long)t * 16384;
        bf16x8 w[4];
#pragma unroll
        for (int i = 0; i < 4; ++i) w[i] = *(const bf16x8*)(ttb + i * 1024);
        __builtin_amdgcn_s_setprio(1);
#pragma unroll
        for (int dt = 0; dt < 16; ++dt) {
            o[dt] = mfma16(w[dt & 3], pk, o[dt]);
            if (dt < 12) w[dt & 3] = *(const bf16x8*)(ttb + (dt + 4) * 1024);
        }
        __builtin_amdgcn_s_setprio(0);
    }

    // ---- epilogue: write partials; lane owns q-row lo; d = dt*16 + 4*hi + r ----
    l += __shfl_xor(l, 16);
    l += __shfl_xor(l, 32);
    long orow = ((((long)b * 32 + qb) * 2 + half) * 64 + wave * 16 + lo) * 256;
#pragma unroll
    for (int dt = 0; dt < 16; ++dt) {
        bf16x4 ov;
        ov[0] = (bf16)o[dt][0]; ov[1] = (bf16)o[dt][1];
        ov[2] = (bf16)o[dt][2]; ov[3] = (bf16)o[dt][3];
        *(bf16x4*)(oPart + orow + dt * 16 + hi * 4) = ov;
    }
    if (hi == 0) {
        long li = ((((long)b * 32 + qb) * 2 + half) * 64 + wave * 16 + lo) * 4;
        lmt[li + 0] = l; lmt[li + 1] = m; lmt[li + 2] = tm;
    }
}

// ================= gemm_out_merge: merge kv-halves + gate + final GEMM =======================
// gated[r][c] = (q + oA*aA/L + oB*aB/L) * sigmoid(max(tmA,tmB)*ln2); out = gated @ w1^T + b1
__global__ __launch_bounds__(256) void gemm_out_merge(const float* __restrict__ qg,
                                                      const bf16* __restrict__ oPart,
                                                      const float* __restrict__ lmt,
                                                      const float* __restrict__ w1,
                                                      const float* __restrict__ b1,
                                                      float* __restrict__ out) {
    __shared__ __align__(16) char smem[55296];
    bf16* Xl   = (bf16*)smem;                  // [64][264]
    char* WlB  = smem + 33792;                 // [256][40]
    float* sRow = (float*)(smem + 54272);      // [64][4]: f0, f1, prob
    const int tid  = threadIdx.x;
    const int lane = tid & 63, wave = tid >> 6;
    const int hi = lane >> 4, lo = lane & 15;
    const long rowbase = (long)blockIdx.x * 64;
    const int b  = (int)(rowbase >> 11);
    const int qb = (int)(rowbase >> 6) & 31;
    const long obase = (((long)b * 32 + qb) * 2) * 16384;
    const int lbase  = ((b * 32 + qb) * 2) * 64;

    if (tid < 64) {
        float lA = lmt[(lbase + tid) * 4 + 0];
        float mA = lmt[(lbase + tid) * 4 + 1];
        float tA = lmt[(lbase + tid) * 4 + 2];
        float lB = lmt[(lbase + 64 + tid) * 4 + 0];
        float mB = lmt[(lbase + 64 + tid) * 4 + 1];
        float tB = lmt[(lbase + 64 + tid) * 4 + 2];
        float M  = fmaxf(mA, mB);
        float aA = exp2f(mA - M), aB = exp2f(mB - M);
        float invl = 1.f / (lA * aA + lB * aB);
        sRow[tid * 4 + 0] = aA * invl;
        sRow[tid * 4 + 1] = aB * invl;
        sRow[tid * 4 + 2] = 1.f / (1.f + __expf(-fmaxf(tA, tB) * 0.69314718f));
    }
    __syncthreads();

    // stage gated (merged) into Xl as bf16
#pragma unroll
    for (int i = 0; i < 16; ++i) {
        int idx4 = i * 256 + tid;
        int e = idx4 * 4;
        int r = e >> 8, c = e & 255;
        float4 qv = *(const float4*)(qg + (rowbase + r) * 256 + c);
        bf16x4 oa = *(const bf16x4*)(oPart + obase + r * 256 + c);
        bf16x4 ob = *(const bf16x4*)(oPart + obase + 16384 + r * 256 + c);
        float f0 = sRow[r * 4 + 0], f1 = sRow[r * 4 + 1], pr = sRow[r * 4 + 2];
        bf16x4 g;
        g[0] = (bf16)((qv.x + (float)oa[0] * f0 + (float)ob[0] * f1) * pr);
        g[1] = (bf16)((qv.y + (float)oa[1] * f0 + (float)ob[1] * f1) * pr);
        g[2] = (bf16)((qv.z + (float)oa[2] * f0 + (float)ob[2] * f1) * pr);
        g[3] = (bf16)((qv.w + (float)oa[3] * f0 + (float)ob[3] * f1) * pr);
        *(bf16x4*)(Xl + r * 264 + c) = g;
    }

    f32x4 acc[16];
    const f32x4 zero = {0.f, 0.f, 0.f, 0.f};
#pragma unroll
    for (int n = 0; n < 16; ++n) acc[n] = zero;

    for (int ks = 0; ks < 8; ++ks) {
        __syncthreads();
#pragma unroll
        for (int c = 0; c < 8; ++c) {
            int idx = c * 256 + tid;
            int e = idx >> 3, q4 = (idx & 7) * 4;
            float4 v = *(const float4*)(w1 + e * 256 + ks * 32 + q4);
            bf16x4 o;
            o[0] = (bf16)v.x; o[1] = (bf16)v.y; o[2] = (bf16)v.z; o[3] = (bf16)v.w;
            *(bf16x4*)(WlB + e * 80 + q4 * 2) = o;
        }
        __syncthreads();
        bf16x8 a = *(const bf16x8*)((const char*)Xl + (wave * 16 + lo) * 528 + ks * 64 + hi * 16);
#pragma unroll
        for (int n = 0; n < 16; ++n) {
            bf16x8 bfr = *(const bf16x8*)(WlB + (n * 16 + lo) * 80 + hi * 16);
            acc[n] = mfma16(a, bfr, acc[n]);
        }
    }

#pragma unroll
    for (int n = 0; n < 16; ++n) {
        int col = n * 16 + lo;
        float bv = b1[col];
#pragma unroll
        for (int r = 0; r < 4; ++r) {
            long row = rowbase + wave * 16 + hi * 4 + r;
            out[row * 256 + col] = acc[n][r] + bv;
        }
    }
}

extern "C" void kernel_launch(void* const* d_in, const int* in_sizes, int n_in,
                              void* d_out, int out_size, void* d_ws, size_t ws_size,
                              hipStream_t stream) {
    const float* q    = (const float*)d_in[0];
    const float* k    = (const float*)d_in[1];
    const float* tsp  = (const float*)d_in[2];
    const float* w_qk = (const float*)d_in[3];
    const float* w1   = (const float*)d_in[4];
    const float* b1   = (const float*)d_in[5];
    float* out = (float*)d_out;
    char* ws = (char*)d_ws;

    bf16*  qp_b  = (bf16*)(ws + 0);           // 16 MB
    bf16*  kp_b  = (bf16*)(ws + 16777216);    // 16 MB
    bf16*  tspF  = (bf16*)(ws + 33554432);    // 16 MB (frag layout)
    bf16*  oPart = (bf16*)(ws + 50331648);    // 32 MB (partial O, bf16)
    float* lmt   = (float*)(ws + 83886080);   // 1 MB  (l, m, tm per row-half)

    prep_qk<<<3072, 256, 0, stream>>>(q, k, w_qk, tsp, qp_b, kp_b, tspF);

    flash10<<<1024, 256, 0, stream>>>(qp_b, kp_b, tspF, oPart, lmt);

    gemm_out_merge<<<512, 256, 0, stream>>>(q, oPart, lmt, w1, b1, out);
}

// Round 12
// 259.677 us; speedup vs baseline: 1.2786x; 1.2786x over previous
//
#include <hip/hip_runtime.h>
#include <hip/hip_bf16.h>

typedef __bf16 bf16;
typedef __bf16 bf16x8 __attribute__((ext_vector_type(8)));
typedef __bf16 bf16x4 __attribute__((ext_vector_type(4)));
typedef __bf16 bf16x2 __attribute__((ext_vector_type(2)));
typedef float f32x4 __attribute__((ext_vector_type(4)));

static __device__ __forceinline__ f32x4 mfma16(bf16x8 a, bf16x8 b, f32x4 c) {
    return __builtin_amdgcn_mfma_f32_16x16x32_bf16(a, b, c, 0, 0, 0);
}

static __device__ __forceinline__ void load16_to_lds(const void* g, void* l) {
    __builtin_amdgcn_global_load_lds(
        (const __attribute__((address_space(1))) unsigned int*)g,
        (__attribute__((address_space(3))) unsigned int*)l, 16, 0, 0);
}

#define LKV 2048
#define DM 256

// ================= shared GEMM body: Y[64 x 256] = X * W^T, W read as f32 =================
template<bool IN_BF16, bool OUT_BF16, bool HAS_BIAS>
static __device__ __forceinline__ void gemm_body(char* smem,
                                                 const void* __restrict__ Xv,
                                                 const float* __restrict__ Wf,
                                                 const float* __restrict__ bias,
                                                 float scale, void* __restrict__ Y,
                                                 long rowbase) {
    bf16* Xl  = (bf16*)smem;            // [64][264] bf16 (528B rows)
    char* WlB = smem + 33792;           // [256][40] bf16 (80B rows)
    const int tid  = threadIdx.x;
    const int lane = tid & 63, wave = tid >> 6;
    const int hi = lane >> 4, lo = lane & 15;

    if (IN_BF16) {
        const bf16* Xb = (const bf16*)Xv;
#pragma unroll
        for (int i = 0; i < 8; ++i) {
            int idx = i * 256 + tid;
            int r = idx >> 5, c8 = (idx & 31) * 8;
            uint4 v = *(const uint4*)(Xb + (rowbase + r) * 256 + c8);
            *(uint4*)(Xl + r * 264 + c8) = v;
        }
    } else {
        const float* X = (const float*)Xv;
#pragma unroll
        for (int i = 0; i < 16; ++i) {
            int idx4 = i * 256 + tid;
            int e = idx4 * 4;
            int r = e >> 8, c = e & 255;
            float4 v = *(const float4*)(X + (rowbase + r) * 256 + c);
            bf16x4 o;
            o[0] = (bf16)v.x; o[1] = (bf16)v.y; o[2] = (bf16)v.z; o[3] = (bf16)v.w;
            *(bf16x4*)(Xl + r * 264 + c) = o;
        }
    }

    f32x4 acc[16];
    const f32x4 zero = {0.f, 0.f, 0.f, 0.f};
#pragma unroll
    for (int n = 0; n < 16; ++n) acc[n] = zero;

    for (int ks = 0; ks < 8; ++ks) {
        __syncthreads();
#pragma unroll
        for (int c = 0; c < 8; ++c) {
            int idx = c * 256 + tid;            // 2048 float4 chunks
            int e = idx >> 3, q4 = (idx & 7) * 4;
            float4 v = *(const float4*)(Wf + e * 256 + ks * 32 + q4);
            bf16x4 o;
            o[0] = (bf16)v.x; o[1] = (bf16)v.y; o[2] = (bf16)v.z; o[3] = (bf16)v.w;
            *(bf16x4*)(WlB + e * 80 + q4 * 2) = o;
        }
        __syncthreads();
        bf16x8 a = *(const bf16x8*)((const char*)Xl + (wave * 16 + lo) * 528 + ks * 64 + hi * 16);
#pragma unroll
        for (int n = 0; n < 16; ++n) {
            bf16x8 bfr = *(const bf16x8*)(WlB + (n * 16 + lo) * 80 + hi * 16);
            acc[n] = mfma16(a, bfr, acc[n]);
        }
    }

#pragma unroll
    for (int n = 0; n < 16; ++n) {
        int col = n * 16 + lo;
        float bv = HAS_BIAS ? bias[col] : 0.f;
#pragma unroll
        for (int r = 0; r < 4; ++r) {
            long row = rowbase + wave * 16 + hi * 4 + r;
            float v = acc[n][r] * scale + bv;
            if (OUT_BF16) ((bf16*)Y)[row * 256 + col] = (bf16)v;
            else          ((float*)Y)[row * 256 + col] = v;
        }
    }
}

// ================= prep_qk: blocks [0,1024) = q/k projection; [1024,3072) = tsp -> tspF ======
// tspF frag layout: byte addr = b*1MB + ((t32*16 + dt)*64 + fl)*16,
// holding tspT[d = dt*16 + (fl&15)][kv = t32*32 + (fl>>4)*8 .. +7] as bf16x8.
__global__ __launch_bounds__(256) void prep_qk(const float* __restrict__ q,
                                               const float* __restrict__ k,
                                               const float* __restrict__ wqk,
                                               const float* __restrict__ tsp,
                                               bf16* __restrict__ qp,
                                               bf16* __restrict__ kp,
                                               bf16* __restrict__ tspF) {
    __shared__ __align__(16) char smem[54272];
    const int tid = threadIdx.x;
    int bid = (int)blockIdx.x;
    if (bid < 1024) {
        bool is_k = bid >= 512;
        // qp scale folds 1/temperature (1/16) AND log2e (exp2-based softmax)
        gemm_body<false, true, false>(smem, is_k ? k : q, wqk, nullptr,
                                      is_k ? 1.0f : 0.09016844f, is_k ? kp : qp,
                                      (long)(bid & 511) * 64);
        return;
    }
    int id = bid - 1024;                       // 2048 tiles: 16 b x 32 kv-tiles x 4 d-tiles
    const int b = id >> 7;
    const int kv0 = (id & 31) * 64, d0 = ((id >> 5) & 3) * 64;
    float (*tile)[65] = (float(*)[65])smem;
#pragma unroll
    for (int i = 0; i < 4; ++i) {
        int idx = i * 256 + tid;
        int kv = idx >> 4, c4 = (idx & 15) * 4;
        float4 v = *(const float4*)(tsp + ((long)(b * LKV + kv0 + kv)) * DM + d0 + c4);
        tile[kv][c4 + 0] = v.x; tile[kv][c4 + 1] = v.y;
        tile[kv][c4 + 2] = v.z; tile[kv][c4 + 3] = v.w;
    }
    __syncthreads();
    char* outb = (char*)tspF + ((long)b << 20);
#pragma unroll
    for (int i = 0; i < 2; ++i) {
        int w = i * 256 + tid;
        int ti = w >> 8;
        int dti = (w >> 6) & 3;
        int fl = w & 63;
        int hi = fl >> 4, lo = fl & 15;
        bf16x8 o;
#pragma unroll
        for (int j = 0; j < 8; ++j) o[j] = (bf16)tile[ti * 32 + hi * 8 + j][dti * 16 + lo];
        int t_abs = (kv0 >> 5) + ti;
        int dt_abs = (d0 >> 4) + dti;
        *(bf16x8*)(outb + (((t_abs * 16 + dt_abs) << 6) + fl) * 16) = o;
    }
}

// ================= flash11: 32 q/wave (2 groups), kv-halved blocks, 2 waves/SIMD =============
// grid = 512 XCD-swizzled: block = (batch, 128 q-rows, kv-half); 4 waves x 32 q; 32 phases.
// kk/tt fragments each feed TWO MFMAs (groups share B-operands) -> bytes/MFMA halved.
// kp dbuf in LDS (32KB); tsp frags from L1 (tspF); partials to ws, merged in gemm_out_merge.
__global__ __launch_bounds__(256, 2) void flash11(const bf16* __restrict__ qp,
                                                  const bf16* __restrict__ kp,
                                                  const bf16* __restrict__ tspF,
                                                  bf16* __restrict__ oPart,
                                                  float* __restrict__ lmt) {
    __shared__ __align__(16) char kbuf[2][16384];   // [kv][512B], chunk i ^= (kv&7)
    const int tid  = threadIdx.x;
    const int lane = tid & 63, wave = tid >> 6;
    const int hi = lane >> 4, lo = lane & 15;

    int id  = (int)blockIdx.x;
    int bid = (id & 7) * 64 + (id >> 3);       // 8 XCDs x 64 blocks -> 2 batches/XCD
    const int b    = bid >> 5;
    const int sub  = bid & 31;
    const int qblk = sub >> 1;                 // 16 q-blocks of 128 rows
    const int half = sub & 1;
    const long qbase  = (long)b * LKV + qblk * 128;
    const char* kp_g  = (const char*)(kp + (long)b * LKV * DM) + half * 524288;
    const char* tsp_f = (const char*)tspF + ((long)b << 20) + (long)half * 524288 + lane * 16;

    int kp_off[4];
#pragma unroll
    for (int j = 0; j < 4; ++j) {
        int kv = wave * 8 + j * 2 + (lane >> 5);
        kp_off[j] = kv * 512 + (((lane & 31) ^ (kv & 7)) << 4);
    }
    int bp_src[4];
#pragma unroll
    for (int k2 = 0; k2 < 4; ++k2)
        bp_src[k2] = ((((hi & 1) * 2 + (k2 >> 1)) << 4) + lo) << 2;
    const int kswz = (lo & 7) << 4;

    // q fragments: two 16-row groups per wave (resident -> kk reuse x2)
    bf16x8 aq[2][8];
#pragma unroll
    for (int g = 0; g < 2; ++g) {
        const bf16* qrow = qp + (qbase + wave * 32 + g * 16 + lo) * DM;
#pragma unroll
        for (int ks = 0; ks < 8; ++ks) aq[g][ks] = *(const bf16x8*)(qrow + ks * 32 + hi * 8);
    }

    f32x4 o[2][16];
    const f32x4 zero = {0.f, 0.f, 0.f, 0.f};
#pragma unroll
    for (int g = 0; g < 2; ++g)
#pragma unroll
        for (int n = 0; n < 16; ++n) o[g][n] = zero;
    float m[2] = {-1e30f, -1e30f}, tm[2] = {-1e30f, -1e30f}, l[2] = {0.f, 0.f};

    // prologue: DMA tile 0 -> slot 0
#pragma unroll
    for (int j = 0; j < 4; ++j)
        load16_to_lds(kp_g + kp_off[j], &kbuf[0][wave * 4096 + j * 1024]);

    for (int t = 0; t < 32; ++t) {
        asm volatile("s_waitcnt vmcnt(0)" ::: "memory");
        __builtin_amdgcn_sched_barrier(0);
        __builtin_amdgcn_s_barrier();
        __builtin_amdgcn_sched_barrier(0);

        // issue DMA(t+1) immediately (slot everyone finished reading in phase t-1)
        if (t < 31) {
            const char* src = kp_g + (long)(t + 1) * 16384;
            char* dst = &kbuf[(t + 1) & 1][wave * 4096];
#pragma unroll
            for (int j = 0; j < 4; ++j)
                load16_to_lds(src + kp_off[j], dst + j * 1024);
        }

        // ---- QK(t): 16 kk reads -> 32 MFMAs (both groups share kk) ----
        f32x4 s[2][2];
        s[0][0] = zero; s[0][1] = zero; s[1][0] = zero; s[1][1] = zero;
        const char* kb = kbuf[t & 1];
        __builtin_amdgcn_s_setprio(1);
#pragma unroll
        for (int ks = 0; ks < 8; ++ks) {
            bf16x8 k0 = *(const bf16x8*)(kb + (lo << 9) + ((ks * 64 + hi * 16) ^ kswz));
            bf16x8 k1 = *(const bf16x8*)(kb + ((16 + lo) << 9) + ((ks * 64 + hi * 16) ^ kswz));
            s[0][0] = mfma16(k0, aq[0][ks], s[0][0]);
            s[0][1] = mfma16(k1, aq[0][ks], s[0][1]);
            s[1][0] = mfma16(k0, aq[1][ks], s[1][0]);
            s[1][1] = mfma16(k1, aq[1][ks], s[1][1]);
        }
        __builtin_amdgcn_s_setprio(0);

        // ---- softmax(t): per-lane for q=lo, both groups (exp2 domain) ----
        float pm[2];
#pragma unroll
        for (int g = 0; g < 2; ++g) {
            float v = fmaxf(fmaxf(fmaxf(s[g][0][0], s[g][0][1]), fmaxf(s[g][0][2], s[g][0][3])),
                            fmaxf(fmaxf(s[g][1][0], s[g][1][1]), fmaxf(s[g][1][2], s[g][1][3])));
            v = fmaxf(v, __shfl_xor(v, 16));
            v = fmaxf(v, __shfl_xor(v, 32));
            pm[g] = v;
            tm[g] = fmaxf(tm[g], v);
        }
        bool need = (pm[0] > m[0] + 11.5f) || (pm[1] > m[1] + 11.5f);
        if (__any(need)) {
#pragma unroll
            for (int g = 0; g < 2; ++g) {
                float nm = fmaxf(m[g], pm[g]);
                float a = exp2f(m[g] - nm);
                m[g] = nm;
                l[g] *= a;
#pragma unroll
                for (int n = 0; n < 16; ++n) o[g][n] *= a;
            }
        }
        bf16x8 pk[2];
#pragma unroll
        for (int g = 0; g < 2; ++g) {
            float p0 = exp2f(s[g][0][0] - m[g]), p1 = exp2f(s[g][0][1] - m[g]);
            float p2 = exp2f(s[g][0][2] - m[g]), p3 = exp2f(s[g][0][3] - m[g]);
            float p4 = exp2f(s[g][1][0] - m[g]), p5 = exp2f(s[g][1][1] - m[g]);
            float p6 = exp2f(s[g][1][2] - m[g]), p7 = exp2f(s[g][1][3] - m[g]);
            l[g] += (p0 + p1) + (p2 + p3) + (p4 + p5) + (p6 + p7);
            int cvt[2][2];
            bf16x2 pr;
            pr[0] = (bf16)p0; pr[1] = (bf16)p1; cvt[0][0] = __builtin_bit_cast(int, pr);
            pr[0] = (bf16)p2; pr[1] = (bf16)p3; cvt[0][1] = __builtin_bit_cast(int, pr);
            pr[0] = (bf16)p4; pr[1] = (bf16)p5; cvt[1][0] = __builtin_bit_cast(int, pr);
            pr[0] = (bf16)p6; pr[1] = (bf16)p7; cvt[1][1] = __builtin_bit_cast(int, pr);
            int pki[4];
#pragma unroll
            for (int k2 = 0; k2 < 4; ++k2) {
                int a0 = __builtin_amdgcn_ds_bpermute(bp_src[k2], cvt[0][k2 & 1]);
                int a1 = __builtin_amdgcn_ds_bpermute(bp_src[k2], cvt[1][k2 & 1]);
                pki[k2] = (hi < 2) ? a0 : a1;
            }
            int4 pii = make_int4(pki[0], pki[1], pki[2], pki[3]);
            pk[g] = __builtin_bit_cast(bf16x8, pii);   // P[q=lo][kv = 8*hi + j]
        }

        // ---- PV(t): tt streamed 4-deep from L1; each tt frag feeds both groups ----
        const char* ttb = tsp_f + (long)t * 16384;
        bf16x8 w[4];
#pragma unroll
        for (int i = 0; i < 4; ++i) w[i] = *(const bf16x8*)(ttb + i * 1024);
        __builtin_amdgcn_s_setprio(1);
#pragma unroll
        for (int dt = 0; dt < 16; ++dt) {
            o[0][dt] = mfma16(w[dt & 3], pk[0], o[0][dt]);
            o[1][dt] = mfma16(w[dt & 3], pk[1], o[1][dt]);
            if (dt < 12) w[dt & 3] = *(const bf16x8*)(ttb + (dt + 4) * 1024);
        }
        __builtin_amdgcn_s_setprio(0);
    }

    // ---- epilogue: partials to ws (flash10 layout); lane owns q-row lo of each group ----
#pragma unroll
    for (int g = 0; g < 2; ++g) {
        float lg = l[g];
        lg += __shfl_xor(lg, 16);
        lg += __shfl_xor(lg, 32);
        int R = qblk * 128 + wave * 32 + g * 16 + lo;   // row within batch
        int qb64 = R >> 6, rin = R & 63;
        long orow = ((((long)b * 32 + qb64) * 2 + half) * 64 + rin) * 256;
#pragma unroll
        for (int dt = 0; dt < 16; ++dt) {
            bf16x4 ov;
            ov[0] = (bf16)o[g][dt][0]; ov[1] = (bf16)o[g][dt][1];
            ov[2] = (bf16)o[g][dt][2]; ov[3] = (bf16)o[g][dt][3];
            *(bf16x4*)(oPart + orow + dt * 16 + hi * 4) = ov;
        }
        if (hi == 0) {
            long li = ((((long)b * 32 + qb64) * 2 + half) * 64 + rin) * 4;
            lmt[li + 0] = lg; lmt[li + 1] = m[g]; lmt[li + 2] = tm[g];
        }
    }
}

// ================= gemm_out_merge: merge kv-halves + gate + final GEMM =======================
__global__ __launch_bounds__(256) void gemm_out_merge(const float* __restrict__ qg,
                                                      const bf16* __restrict__ oPart,
                                                      const float* __restrict__ lmt,
                                                      const float* __restrict__ w1,
                                                      const float* __restrict__ b1,
                                                      float* __restrict__ out) {
    __shared__ __align__(16) char smem[55296];
    bf16* Xl   = (bf16*)smem;                  // [64][264]
    char* WlB  = smem + 33792;                 // [256][40]
    float* sRow = (float*)(smem + 54272);      // [64][4]: f0, f1, prob
    const int tid  = threadIdx.x;
    const int lane = tid & 63, wave = tid >> 6;
    const int hi = lane >> 4, lo = lane & 15;
    const long rowbase = (long)blockIdx.x * 64;
    const int b  = (int)(rowbase >> 11);
    const int qb = (int)(rowbase >> 6) & 31;
    const long obase = (((long)b * 32 + qb) * 2) * 16384;
    const int lbase  = ((b * 32 + qb) * 2) * 64;

    if (tid < 64) {
        float lA = lmt[(lbase + tid) * 4 + 0];
        float mA = lmt[(lbase + tid) * 4 + 1];
        float tA = lmt[(lbase + tid) * 4 + 2];
        float lB = lmt[(lbase + 64 + tid) * 4 + 0];
        float mB = lmt[(lbase + 64 + tid) * 4 + 1];
        float tB = lmt[(lbase + 64 + tid) * 4 + 2];
        float M  = fmaxf(mA, mB);
        float aA = exp2f(mA - M), aB = exp2f(mB - M);
        float invl = 1.f / (lA * aA + lB * aB);
        sRow[tid * 4 + 0] = aA * invl;
        sRow[tid * 4 + 1] = aB * invl;
        sRow[tid * 4 + 2] = 1.f / (1.f + __expf(-fmaxf(tA, tB) * 0.69314718f));
    }
    __syncthreads();

#pragma unroll
    for (int i = 0; i < 16; ++i) {
        int idx4 = i * 256 + tid;
        int e = idx4 * 4;
        int r = e >> 8, c = e & 255;
        float4 qv = *(const float4*)(qg + (rowbase + r) * 256 + c);
        bf16x4 oa = *(const bf16x4*)(oPart + obase + r * 256 + c);
        bf16x4 ob = *(const bf16x4*)(oPart + obase + 16384 + r * 256 + c);
        float f0 = sRow[r * 4 + 0], f1 = sRow[r * 4 + 1], pr = sRow[r * 4 + 2];
        bf16x4 g;
        g[0] = (bf16)((qv.x + (float)oa[0] * f0 + (float)ob[0] * f1) * pr);
        g[1] = (bf16)((qv.y + (float)oa[1] * f0 + (float)ob[1] * f1) * pr);
        g[2] = (bf16)((qv.z + (float)oa[2] * f0 + (float)ob[2] * f1) * pr);
        g[3] = (bf16)((qv.w + (float)oa[3] * f0 + (float)ob[3] * f1) * pr);
        *(bf16x4*)(Xl + r * 264 + c) = g;
    }

    f32x4 acc[16];
    const f32x4 zero = {0.f, 0.f, 0.f, 0.f};
#pragma unroll
    for (int n = 0; n < 16; ++n) acc[n] = zero;

    for (int ks = 0; ks < 8; ++ks) {
        __syncthreads();
#pragma unroll
        for (int c = 0; c < 8; ++c) {
            int idx = c * 256 + tid;
            int e = idx >> 3, q4 = (idx & 7) * 4;
            float4 v = *(const float4*)(w1 + e * 256 + ks * 32 + q4);
            bf16x4 o;
            o[0] = (bf16)v.x; o[1] = (bf16)v.y; o[2] = (bf16)v.z; o[3] = (bf16)v.w;
            *(bf16x4*)(WlB + e * 80 + q4 * 2) = o;
        }
        __syncthreads();
        bf16x8 a = *(const bf16x8*)((const char*)Xl + (wave * 16 + lo) * 528 + ks * 64 + hi * 16);
#pragma unroll
        for (int n = 0; n < 16; ++n) {
            bf16x8 bfr = *(const bf16x8*)(WlB + (n * 16 + lo) * 80 + hi * 16);
            acc[n] = mfma16(a, bfr, acc[n]);
        }
    }

#pragma unroll
    for (int n = 0; n < 16; ++n) {
        int col = n * 16 + lo;
        float bv = b1[col];
#pragma unroll
        for (int r = 0; r < 4; ++r) {
            long row = rowbase + wave * 16 + hi * 4 + r;
            out[row * 256 + col] = acc[n][r] + bv;
        }
    }
}

extern "C" void kernel_launch(void* const* d_in, const int* in_sizes, int n_in,
                              void* d_out, int out_size, void* d_ws, size_t ws_size,
                              hipStream_t stream) {
    const float* q    = (const float*)d_in[0];
    const float* k    = (const float*)d_in[1];
    const float* tsp  = (const float*)d_in[2];
    const float* w_qk = (const float*)d_in[3];
    const float* w1   = (const float*)d_in[4];
    const float* b1   = (const float*)d_in[5];
    float* out = (float*)d_out;
    char* ws = (char*)d_ws;

    bf16*  qp_b  = (bf16*)(ws + 0);           // 16 MB
    bf16*  kp_b  = (bf16*)(ws + 16777216);    // 16 MB
    bf16*  tspF  = (bf16*)(ws + 33554432);    // 16 MB (frag layout)
    bf16*  oPart = (bf16*)(ws + 50331648);    // 32 MB (partial O, bf16)
    float* lmt   = (float*)(ws + 83886080);   // 1 MB  (l, m, tm per row-half)

    prep_qk<<<3072, 256, 0, stream>>>(q, k, w_qk, tsp, qp_b, kp_b, tspF);

    flash11<<<512, 256, 0, stream>>>(qp_b, kp_b, tspF, oPart, lmt);

    gemm_out_merge<<<512, 256, 0, stream>>>(q, oPart, lmt, w1, b1, out);
}

// Round 13
// 167.408 us; speedup vs baseline: 1.9832x; 1.5512x over previous
//
#include <hip/hip_runtime.h>
#include <hip/hip_bf16.h>

typedef __bf16 bf16;
typedef __bf16 bf16x8 __attribute__((ext_vector_type(8)));
typedef __bf16 bf16x4 __attribute__((ext_vector_type(4)));
typedef __bf16 bf16x2 __attribute__((ext_vector_type(2)));
typedef float f32x4 __attribute__((ext_vector_type(4)));

static __device__ __forceinline__ f32x4 mfma16(bf16x8 a, bf16x8 b, f32x4 c) {
    return __builtin_amdgcn_mfma_f32_16x16x32_bf16(a, b, c, 0, 0, 0);
}

static __device__ __forceinline__ void load16_to_lds(const void* g, void* l) {
    __builtin_amdgcn_global_load_lds(
        (const __attribute__((address_space(1))) unsigned int*)g,
        (__attribute__((address_space(3))) unsigned int*)l, 16, 0, 0);
}

#define LKV 2048
#define DM 256

// ================= shared GEMM body: Y[64 x 256] = X * W^T, W read as f32 =================
template<bool IN_BF16, bool OUT_BF16, bool HAS_BIAS>
static __device__ __forceinline__ void gemm_body(char* smem,
                                                 const void* __restrict__ Xv,
                                                 const float* __restrict__ Wf,
                                                 const float* __restrict__ bias,
                                                 float scale, void* __restrict__ Y,
                                                 long rowbase) {
    bf16* Xl  = (bf16*)smem;            // [64][264] bf16 (528B rows)
    char* WlB = smem + 33792;           // [256][40] bf16 (80B rows)
    const int tid  = threadIdx.x;
    const int lane = tid & 63, wave = tid >> 6;
    const int hi = lane >> 4, lo = lane & 15;

    if (IN_BF16) {
        const bf16* Xb = (const bf16*)Xv;
#pragma unroll
        for (int i = 0; i < 8; ++i) {
            int idx = i * 256 + tid;
            int r = idx >> 5, c8 = (idx & 31) * 8;
            uint4 v = *(const uint4*)(Xb + (rowbase + r) * 256 + c8);
            *(uint4*)(Xl + r * 264 + c8) = v;
        }
    } else {
        const float* X = (const float*)Xv;
#pragma unroll
        for (int i = 0; i < 16; ++i) {
            int idx4 = i * 256 + tid;
            int e = idx4 * 4;
            int r = e >> 8, c = e & 255;
            float4 v = *(const float4*)(X + (rowbase + r) * 256 + c);
            bf16x4 o;
            o[0] = (bf16)v.x; o[1] = (bf16)v.y; o[2] = (bf16)v.z; o[3] = (bf16)v.w;
            *(bf16x4*)(Xl + r * 264 + c) = o;
        }
    }

    f32x4 acc[16];
    const f32x4 zero = {0.f, 0.f, 0.f, 0.f};
#pragma unroll
    for (int n = 0; n < 16; ++n) acc[n] = zero;

    for (int ks = 0; ks < 8; ++ks) {
        __syncthreads();
#pragma unroll
        for (int c = 0; c < 8; ++c) {
            int idx = c * 256 + tid;            // 2048 float4 chunks
            int e = idx >> 3, q4 = (idx & 7) * 4;
            float4 v = *(const float4*)(Wf + e * 256 + ks * 32 + q4);
            bf16x4 o;
            o[0] = (bf16)v.x; o[1] = (bf16)v.y; o[2] = (bf16)v.z; o[3] = (bf16)v.w;
            *(bf16x4*)(WlB + e * 80 + q4 * 2) = o;
        }
        __syncthreads();
        bf16x8 a = *(const bf16x8*)((const char*)Xl + (wave * 16 + lo) * 528 + ks * 64 + hi * 16);
#pragma unroll
        for (int n = 0; n < 16; ++n) {
            bf16x8 bfr = *(const bf16x8*)(WlB + (n * 16 + lo) * 80 + hi * 16);
            acc[n] = mfma16(a, bfr, acc[n]);
        }
    }

#pragma unroll
    for (int n = 0; n < 16; ++n) {
        int col = n * 16 + lo;
        float bv = HAS_BIAS ? bias[col] : 0.f;
#pragma unroll
        for (int r = 0; r < 4; ++r) {
            long row = rowbase + wave * 16 + hi * 4 + r;
            float v = acc[n][r] * scale + bv;
            if (OUT_BF16) ((bf16*)Y)[row * 256 + col] = (bf16)v;
            else          ((float*)Y)[row * 256 + col] = v;
        }
    }
}

// ================= prep_qk: blocks [0,1024) = q/k projection; [1024,3072) = tsp -> tspF ======
// tspF frag layout: byte addr = b*1MB + ((t32*16 + dt)*64 + fl)*16,
// holding tspT[d = dt*16 + (fl&15)][kv = t32*32 + (fl>>4)*8 .. +7] as bf16x8.
__global__ __launch_bounds__(256) void prep_qk(const float* __restrict__ q,
                                               const float* __restrict__ k,
                                               const float* __restrict__ wqk,
                                               const float* __restrict__ tsp,
                                               bf16* __restrict__ qp,
                                               bf16* __restrict__ kp,
                                               bf16* __restrict__ tspF) {
    __shared__ __align__(16) char smem[54272];
    const int tid = threadIdx.x;
    int bid = (int)blockIdx.x;
    if (bid < 1024) {
        bool is_k = bid >= 512;
        // qp scale folds 1/temperature (1/16) AND log2e (exp2-based softmax)
        gemm_body<false, true, false>(smem, is_k ? k : q, wqk, nullptr,
                                      is_k ? 1.0f : 0.09016844f, is_k ? kp : qp,
                                      (long)(bid & 511) * 64);
        return;
    }
    int id = bid - 1024;                       // 2048 tiles: 16 b x 32 kv-tiles x 4 d-tiles
    const int b = id >> 7;
    const int kv0 = (id & 31) * 64, d0 = ((id >> 5) & 3) * 64;
    float (*tile)[65] = (float(*)[65])smem;
#pragma unroll
    for (int i = 0; i < 4; ++i) {
        int idx = i * 256 + tid;
        int kv = idx >> 4, c4 = (idx & 15) * 4;
        float4 v = *(const float4*)(tsp + ((long)(b * LKV + kv0 + kv)) * DM + d0 + c4);
        tile[kv][c4 + 0] = v.x; tile[kv][c4 + 1] = v.y;
        tile[kv][c4 + 2] = v.z; tile[kv][c4 + 3] = v.w;
    }
    __syncthreads();
    char* outb = (char*)tspF + ((long)b << 20);
#pragma unroll
    for (int i = 0; i < 2; ++i) {
        int w = i * 256 + tid;
        int ti = w >> 8;
        int dti = (w >> 6) & 3;
        int fl = w & 63;
        int hi = fl >> 4, lo = fl & 15;
        bf16x8 o;
#pragma unroll
        for (int j = 0; j < 8; ++j) o[j] = (bf16)tile[ti * 32 + hi * 8 + j][dti * 16 + lo];
        int t_abs = (kv0 >> 5) + ti;
        int dt_abs = (d0 >> 4) + dti;
        *(bf16x8*)(outb + (((t_abs * 16 + dt_abs) << 6) + fl) * 16) = o;
    }
}

// ================= gemm_out: out = gated(bf16) @ w1^T + b1, f32 out ==========================
__global__ __launch_bounds__(256) void gemm_out(const bf16* __restrict__ gated,
                                                const float* __restrict__ w1,
                                                const float* __restrict__ b1,
                                                float* __restrict__ out) {
    __shared__ __align__(16) char smem[54272];
    gemm_body<true, false, true>(smem, gated, w1, b1, 1.0f, out, (long)blockIdx.x * 64);
}

// ================= flash12: flash6 skeleton + cross-tile PV ==================================
// grid = 512 XCD-swizzled, block = 256 (4 waves, lane owns q = lane&15). KV tile = 32,
// 64 phases. kp 3-slot LDS (DMA); tsp frags from L1 (tspF), held across the phase boundary.
// Phase t: vmcnt(N) -> barrier -> QK(t) || PV(t-1) -> reload tt(t) -> DMA kp(t+2)
//          -> softmax(t) -> pk(t).  Tail: PV(63).
__global__ __launch_bounds__(256, 2) void flash12(const bf16* __restrict__ qp,
                                                  const bf16* __restrict__ kp,
                                                  const bf16* __restrict__ tspF,
                                                  const float* __restrict__ qorig,
                                                  bf16* __restrict__ gated) {
    __shared__ __align__(16) char kbuf[3][16384];   // [kv][512B], chunk i ^= (kv&7)
    const int tid  = threadIdx.x;
    const int lane = tid & 63, wave = tid >> 6;
    const int hi = lane >> 4, lo = lane & 15;

    int id  = (int)blockIdx.x;
    int bid = (id & 7) * 64 + (id >> 3);
    const int b  = bid >> 5;
    const int qb = bid & 31;
    const long qbase = (long)b * LKV + qb * 64;
    const char* kp_g  = (const char*)(kp + (long)b * LKV * DM);
    const char* tsp_f = (const char*)tspF + ((long)b << 20) + lane * 16;

    int kp_off[4];
#pragma unroll
    for (int j = 0; j < 4; ++j) {
        int kv = wave * 8 + j * 2 + (lane >> 5);
        kp_off[j] = kv * 512 + (((lane & 31) ^ (kv & 7)) << 4);
    }
    int bp_src[4];
#pragma unroll
    for (int k2 = 0; k2 < 4; ++k2)
        bp_src[k2] = ((((hi & 1) * 2 + (k2 >> 1)) << 4) + lo) << 2;
    const int kswz = (lo & 7) << 4;

    // q fragments: lane's q-row is lo
    bf16x8 aq[8];
    {
        const bf16* qrow = qp + (qbase + wave * 16 + lo) * DM;
#pragma unroll
        for (int ks = 0; ks < 8; ++ks) aq[ks] = *(const bf16x8*)(qrow + ks * 32 + hi * 8);
    }

    f32x4 o[16];
    const f32x4 zero = {0.f, 0.f, 0.f, 0.f};
#pragma unroll
    for (int n = 0; n < 16; ++n) o[n] = zero;
    float m = -1e30f, tm = -1e30f, l = 0.f;
    bf16x8 pk;
#pragma unroll
    for (int j = 0; j < 8; ++j) pk[j] = (bf16)0.0f;
    bf16x8 tt[16];

    // prologue: DMA kp tiles 0,1 into slots 0,1
#pragma unroll
    for (int j = 0; j < 4; ++j)
        load16_to_lds(kp_g + kp_off[j],          &kbuf[0][wave * 4096 + j * 1024]);
#pragma unroll
    for (int j = 0; j < 4; ++j)
        load16_to_lds(kp_g + 16384 + kp_off[j],  &kbuf[1][wave * 4096 + j * 1024]);

    for (int t = 0; t < 64; ++t) {
        if (t == 0)       { asm volatile("s_waitcnt vmcnt(4)"  ::: "memory"); }
        else if (t == 63) { asm volatile("s_waitcnt vmcnt(16)" ::: "memory"); }
        else              { asm volatile("s_waitcnt vmcnt(20)" ::: "memory"); }
        __builtin_amdgcn_sched_barrier(0);
        __builtin_amdgcn_s_barrier();
        __builtin_amdgcn_sched_barrier(0);

        // ---- QK(t) (LDS) || PV(t-1) (register-only, tt/pk from phase t-1) ----
        f32x4 s0 = zero, s1 = zero;
        const char* kb = kbuf[t % 3];
        __builtin_amdgcn_s_setprio(1);
#pragma unroll
        for (int ks = 0; ks < 8; ++ks) {
            bf16x8 k0 = *(const bf16x8*)(kb + (lo << 9) + ((ks * 64 + hi * 16) ^ kswz));
            bf16x8 k1 = *(const bf16x8*)(kb + ((16 + lo) << 9) + ((ks * 64 + hi * 16) ^ kswz));
            s0 = mfma16(k0, aq[ks], s0);
            s1 = mfma16(k1, aq[ks], s1);
        }
        if (t > 0) {
#pragma unroll
            for (int dt = 0; dt < 16; ++dt)
                o[dt] = mfma16(tt[dt], pk, o[dt]);
        }
        __builtin_amdgcn_s_setprio(0);

        // ---- reload tt(t) from L1 (PV consumed the old set); hides under softmax ----
        {
            const char* ttb = tsp_f + (long)t * 16384;
#pragma unroll
            for (int dt = 0; dt < 16; ++dt)
                tt[dt] = *(const bf16x8*)(ttb + dt * 1024);
        }
        // ---- DMA kp(t+2) into slot (t+2)%3 (read by all waves in phase t-1; barrier-safe) ----
        if (t < 62) {
            const char* src = kp_g + (long)(t + 2) * 16384;
            char* dst = &kbuf[(t + 2) % 3][wave * 4096];
#pragma unroll
            for (int j = 0; j < 4; ++j)
                load16_to_lds(src + kp_off[j], dst + j * 1024);
        }

        // ---- softmax(t): per-lane for q=lo (exp2 domain), l as scalar partial ----
        float pm = fmaxf(fmaxf(fmaxf(s0[0], s0[1]), fmaxf(s0[2], s0[3])),
                         fmaxf(fmaxf(s1[0], s1[1]), fmaxf(s1[2], s1[3])));
        pm = fmaxf(pm, __shfl_xor(pm, 16));
        pm = fmaxf(pm, __shfl_xor(pm, 32));
        tm = fmaxf(tm, pm);
        if (__any(pm > m + 11.5f)) {      // defer-max: 8 nats = 11.5 bits
            float nm = fmaxf(m, pm);
            float a = exp2f(m - nm);
            m = nm;
            l *= a;
#pragma unroll
            for (int n = 0; n < 16; ++n) o[n] *= a;
        }
        float p0 = exp2f(s0[0] - m), p1 = exp2f(s0[1] - m);
        float p2 = exp2f(s0[2] - m), p3 = exp2f(s0[3] - m);
        float p4 = exp2f(s1[0] - m), p5 = exp2f(s1[1] - m);
        float p6 = exp2f(s1[2] - m), p7 = exp2f(s1[3] - m);
        l += (p0 + p1) + (p2 + p3) + (p4 + p5) + (p6 + p7);
        int cvt[2][2];
        {
            bf16x2 pr;
            pr[0] = (bf16)p0; pr[1] = (bf16)p1; cvt[0][0] = __builtin_bit_cast(int, pr);
            pr[0] = (bf16)p2; pr[1] = (bf16)p3; cvt[0][1] = __builtin_bit_cast(int, pr);
            pr[0] = (bf16)p4; pr[1] = (bf16)p5; cvt[1][0] = __builtin_bit_cast(int, pr);
            pr[0] = (bf16)p6; pr[1] = (bf16)p7; cvt[1][1] = __builtin_bit_cast(int, pr);
        }
        int pki[4];
#pragma unroll
        for (int k2 = 0; k2 < 4; ++k2) {
            int a0 = __builtin_amdgcn_ds_bpermute(bp_src[k2], cvt[0][k2 & 1]);
            int a1 = __builtin_amdgcn_ds_bpermute(bp_src[k2], cvt[1][k2 & 1]);
            pki[k2] = (hi < 2) ? a0 : a1;
        }
        int4 pii = make_int4(pki[0], pki[1], pki[2], pki[3]);
        pk = __builtin_bit_cast(bf16x8, pii);   // P[q=lo][kv = 8*hi + j]
    }

    // ---- tail: PV(63) ----
#pragma unroll
    for (int dt = 0; dt < 16; ++dt)
        o[dt] = mfma16(tt[dt], pk, o[dt]);

    // ---- epilogue: lane owns q-row lo; d = dt*16 + 4*hi + r ----
    l += __shfl_xor(l, 16);
    l += __shfl_xor(l, 32);
    float prob = 1.f / (1.f + __expf(-tm * 0.69314718f));
    float invl = 1.f / l;
    long row = qbase + wave * 16 + lo;
#pragma unroll
    for (int dt = 0; dt < 16; ++dt) {
        int c0 = dt * 16 + hi * 4;
        float4 qv = *(const float4*)(qorig + row * 256 + c0);
        bf16x4 g;
        g[0] = (bf16)((qv.x + o[dt][0] * invl) * prob);
        g[1] = (bf16)((qv.y + o[dt][1] * invl) * prob);
        g[2] = (bf16)((qv.z + o[dt][2] * invl) * prob);
        g[3] = (bf16)((qv.w + o[dt][3] * invl) * prob);
        *(bf16x4*)(gated + row * 256 + c0) = g;
    }
}

extern "C" void kernel_launch(void* const* d_in, const int* in_sizes, int n_in,
                              void* d_out, int out_size, void* d_ws, size_t ws_size,
                              hipStream_t stream) {
    const float* q    = (const float*)d_in[0];
    const float* k    = (const float*)d_in[1];
    const float* tsp  = (const float*)d_in[2];
    const float* w_qk = (const float*)d_in[3];
    const float* w1   = (const float*)d_in[4];
    const float* b1   = (const float*)d_in[5];
    float* out = (float*)d_out;
    char* ws = (char*)d_ws;

    bf16* qp_b  = (bf16*)(ws + 0);           // 16 MB
    bf16* kp_b  = (bf16*)(ws + 16777216);    // 16 MB
    bf16* tspF  = (bf16*)(ws + 33554432);    // 16 MB (frag layout)
    bf16* gated = (bf16*)(ws + 50331648);    // 16 MB

    prep_qk<<<3072, 256, 0, stream>>>(q, k, w_qk, tsp, qp_b, kp_b, tspF);

    flash12<<<512, 256, 0, stream>>>(qp_b, kp_b, tspF, q, gated);

    gemm_out<<<512, 256, 0, stream>>>(gated, w1, b1, out);
}

// Round 14
// 162.668 us; speedup vs baseline: 2.0410x; 1.0291x over previous
//
#include <hip/hip_runtime.h>
#include <hip/hip_bf16.h>

typedef __bf16 bf16;
typedef __bf16 bf16x8 __attribute__((ext_vector_type(8)));
typedef __bf16 bf16x4 __attribute__((ext_vector_type(4)));
typedef __bf16 bf16x2 __attribute__((ext_vector_type(2)));
typedef float f32x4 __attribute__((ext_vector_type(4)));
typedef short s16x4 __attribute__((ext_vector_type(4)));
typedef int   i32x2 __attribute__((ext_vector_type(2)));
typedef int   i32x4 __attribute__((ext_vector_type(4)));

static __device__ __forceinline__ f32x4 mfma16(bf16x8 a, bf16x8 b, f32x4 c) {
    return __builtin_amdgcn_mfma_f32_16x16x32_bf16(a, b, c, 0, 0, 0);
}

// K=16 bf16 MFMA (the "_1k" CDNA encoding carried into gfx950). Fallback: zero-padded K=32.
#if __has_builtin(__builtin_amdgcn_mfma_f32_16x16x16bf16_1k)
static __device__ __forceinline__ f32x4 mfma1k(s16x4 a, s16x4 b, f32x4 c) {
    return __builtin_amdgcn_mfma_f32_16x16x16bf16_1k(a, b, c, 0, 0, 0);
}
#else
static __device__ __forceinline__ f32x4 mfma1k(s16x4 a, s16x4 b, f32x4 c) {
    bf16x8 av, bv;
    bf16x4 a4 = __builtin_bit_cast(bf16x4, a), b4 = __builtin_bit_cast(bf16x4, b);
#pragma unroll
    for (int j = 0; j < 4; ++j) { av[j] = a4[j]; av[j+4] = (bf16)0.f; bv[j] = b4[j]; bv[j+4] = (bf16)0.f; }
    return __builtin_amdgcn_mfma_f32_16x16x32_bf16(av, bv, c, 0, 0, 0);
}
#endif

static __device__ __forceinline__ void load16_to_lds(const void* g, void* l) {
    __builtin_amdgcn_global_load_lds(
        (const __attribute__((address_space(1))) unsigned int*)g,
        (__attribute__((address_space(3))) unsigned int*)l, 16, 0, 0);
}

#define LKV 2048
#define DM 256

// ================= shared GEMM body: Y[64 x 256] = X * W^T, W read as f32 =================
template<bool IN_BF16, bool OUT_BF16, bool HAS_BIAS>
static __device__ __forceinline__ void gemm_body(char* smem,
                                                 const void* __restrict__ Xv,
                                                 const float* __restrict__ Wf,
                                                 const float* __restrict__ bias,
                                                 float scale, void* __restrict__ Y,
                                                 long rowbase) {
    bf16* Xl  = (bf16*)smem;            // [64][264] bf16 (528B rows)
    char* WlB = smem + 33792;           // [256][40] bf16 (80B rows)
    const int tid  = threadIdx.x;
    const int lane = tid & 63, wave = tid >> 6;
    const int hi = lane >> 4, lo = lane & 15;

    if (IN_BF16) {
        const bf16* Xb = (const bf16*)Xv;
#pragma unroll
        for (int i = 0; i < 8; ++i) {
            int idx = i * 256 + tid;
            int r = idx >> 5, c8 = (idx & 31) * 8;
            uint4 v = *(const uint4*)(Xb + (rowbase + r) * 256 + c8);
            *(uint4*)(Xl + r * 264 + c8) = v;
        }
    } else {
        const float* X = (const float*)Xv;
#pragma unroll
        for (int i = 0; i < 16; ++i) {
            int idx4 = i * 256 + tid;
            int e = idx4 * 4;
            int r = e >> 8, c = e & 255;
            float4 v = *(const float4*)(X + (rowbase + r) * 256 + c);
            bf16x4 o;
            o[0] = (bf16)v.x; o[1] = (bf16)v.y; o[2] = (bf16)v.z; o[3] = (bf16)v.w;
            *(bf16x4*)(Xl + r * 264 + c) = o;
        }
    }

    f32x4 acc[16];
    const f32x4 zero = {0.f, 0.f, 0.f, 0.f};
#pragma unroll
    for (int n = 0; n < 16; ++n) acc[n] = zero;

    for (int ks = 0; ks < 8; ++ks) {
        __syncthreads();
#pragma unroll
        for (int c = 0; c < 8; ++c) {
            int idx = c * 256 + tid;            // 2048 float4 chunks
            int e = idx >> 3, q4 = (idx & 7) * 4;
            float4 v = *(const float4*)(Wf + e * 256 + ks * 32 + q4);
            bf16x4 o;
            o[0] = (bf16)v.x; o[1] = (bf16)v.y; o[2] = (bf16)v.z; o[3] = (bf16)v.w;
            *(bf16x4*)(WlB + e * 80 + q4 * 2) = o;
        }
        __syncthreads();
        bf16x8 a = *(const bf16x8*)((const char*)Xl + (wave * 16 + lo) * 528 + ks * 64 + hi * 16);
#pragma unroll
        for (int n = 0; n < 16; ++n) {
            bf16x8 bfr = *(const bf16x8*)(WlB + (n * 16 + lo) * 80 + hi * 16);
            acc[n] = mfma16(a, bfr, acc[n]);
        }
    }

#pragma unroll
    for (int n = 0; n < 16; ++n) {
        int col = n * 16 + lo;
        float bv = HAS_BIAS ? bias[col] : 0.f;
#pragma unroll
        for (int r = 0; r < 4; ++r) {
            long row = rowbase + wave * 16 + hi * 4 + r;
            float v = acc[n][r] * scale + bv;
            if (OUT_BF16) ((bf16*)Y)[row * 256 + col] = (bf16)v;
            else          ((float*)Y)[row * 256 + col] = v;
        }
    }
}

// ================= prep_qk: blocks [0,1024) = q/k projection; [1024,3072) = tsp -> tspF ======
// tspF frag layout (K=16 PV): byte addr = b*1MB + ((t32*16 + dt)*64 + fl)*16, holding
// j=0..3 -> tspT[d = dt*16 + (fl&15)][kv = t32*32 + 4*(fl>>4) + j]
// j=4..7 -> tspT[d][kv = t32*32 + 16 + 4*(fl>>4) + (j-4)]    (matches S^T C row-map)
__global__ __launch_bounds__(256) void prep_qk(const float* __restrict__ q,
                                               const float* __restrict__ k,
                                               const float* __restrict__ wqk,
                                               const float* __restrict__ tsp,
                                               bf16* __restrict__ qp,
                                               bf16* __restrict__ kp,
                                               bf16* __restrict__ tspF) {
    __shared__ __align__(16) char smem[54272];
    const int tid = threadIdx.x;
    int bid = (int)blockIdx.x;
    if (bid < 1024) {
        bool is_k = bid >= 512;
        // qp scale folds 1/temperature (1/16) AND log2e (exp2-based softmax)
        gemm_body<false, true, false>(smem, is_k ? k : q, wqk, nullptr,
                                      is_k ? 1.0f : 0.09016844f, is_k ? kp : qp,
                                      (long)(bid & 511) * 64);
        return;
    }
    int id = bid - 1024;                       // 2048 tiles: 16 b x 32 kv-tiles x 4 d-tiles
    const int b = id >> 7;
    const int kv0 = (id & 31) * 64, d0 = ((id >> 5) & 3) * 64;
    float (*tile)[65] = (float(*)[65])smem;
#pragma unroll
    for (int i = 0; i < 4; ++i) {
        int idx = i * 256 + tid;
        int kv = idx >> 4, c4 = (idx & 15) * 4;
        float4 v = *(const float4*)(tsp + ((long)(b * LKV + kv0 + kv)) * DM + d0 + c4);
        tile[kv][c4 + 0] = v.x; tile[kv][c4 + 1] = v.y;
        tile[kv][c4 + 2] = v.z; tile[kv][c4 + 3] = v.w;
    }
    __syncthreads();
    char* outb = (char*)tspF + ((long)b << 20);
#pragma unroll
    for (int i = 0; i < 2; ++i) {
        int w = i * 256 + tid;
        int ti = w >> 8;
        int dti = (w >> 6) & 3;
        int fl = w & 63;
        int hi = fl >> 4, lo = fl & 15;
        bf16x8 o;
#pragma unroll
        for (int j = 0; j < 8; ++j)
            o[j] = (bf16)tile[ti * 32 + hi * 4 + (j & 3) + ((j >> 2) << 4)][dti * 16 + lo];
        int t_abs = (kv0 >> 5) + ti;
        int dt_abs = (d0 >> 4) + dti;
        *(bf16x8*)(outb + (((t_abs * 16 + dt_abs) << 6) + fl) * 16) = o;
    }
}

// ================= gemm_out: out = gated(bf16) @ w1^T + b1, f32 out ==========================
__global__ __launch_bounds__(256) void gemm_out(const bf16* __restrict__ gated,
                                                const float* __restrict__ w1,
                                                const float* __restrict__ b1,
                                                float* __restrict__ out) {
    __shared__ __align__(16) char smem[54272];
    gemm_body<true, false, true>(smem, gated, w1, b1, 1.0f, out, (long)blockIdx.x * 64);
}

// ================= flash13: flash12 + exchange-free K=16 PV ==================================
// grid = 512 XCD-swizzled, block = 256 (4 waves, lane owns q = lane&15). KV tile = 32,
// 64 phases. kp 3-slot LDS (DMA); tsp K=16 frags from L1 (tspF), held across phase boundary.
// Phase t: vmcnt(N) -> barrier -> QK(t) || PV(t-1) -> reload tt(t) -> DMA kp(t+2)
//          -> softmax(t) -> pk0/pk1 (NO cross-lane exchange).  Tail: PV(63).
__global__ __launch_bounds__(256, 2) void flash13(const bf16* __restrict__ qp,
                                                  const bf16* __restrict__ kp,
                                                  const bf16* __restrict__ tspF,
                                                  const float* __restrict__ qorig,
                                                  bf16* __restrict__ gated) {
    __shared__ __align__(16) char kbuf[3][16384];   // [kv][512B], chunk i ^= (kv&7)
    const int tid  = threadIdx.x;
    const int lane = tid & 63, wave = tid >> 6;
    const int hi = lane >> 4, lo = lane & 15;

    int id  = (int)blockIdx.x;
    int bid = (id & 7) * 64 + (id >> 3);
    const int b  = bid >> 5;
    const int qb = bid & 31;
    const long qbase = (long)b * LKV + qb * 64;
    const char* kp_g  = (const char*)(kp + (long)b * LKV * DM);
    const char* tsp_f = (const char*)tspF + ((long)b << 20) + lane * 16;

    int kp_off[4];
#pragma unroll
    for (int j = 0; j < 4; ++j) {
        int kv = wave * 8 + j * 2 + (lane >> 5);
        kp_off[j] = kv * 512 + (((lane & 31) ^ (kv & 7)) << 4);
    }
    const int kswz = (lo & 7) << 4;

    // q fragments: lane's q-row is lo
    bf16x8 aq[8];
    {
        const bf16* qrow = qp + (qbase + wave * 16 + lo) * DM;
#pragma unroll
        for (int ks = 0; ks < 8; ++ks) aq[ks] = *(const bf16x8*)(qrow + ks * 32 + hi * 8);
    }

    f32x4 o[16];
    const f32x4 zero = {0.f, 0.f, 0.f, 0.f};
#pragma unroll
    for (int n = 0; n < 16; ++n) o[n] = zero;
    float m = -1e30f, tm = -1e30f, l = 0.f;
    s16x4 pk0 = {0, 0, 0, 0}, pk1 = {0, 0, 0, 0};
    bf16x8 tt[16];

    // prologue: DMA kp tiles 0,1 into slots 0,1
#pragma unroll
    for (int j = 0; j < 4; ++j)
        load16_to_lds(kp_g + kp_off[j],          &kbuf[0][wave * 4096 + j * 1024]);
#pragma unroll
    for (int j = 0; j < 4; ++j)
        load16_to_lds(kp_g + 16384 + kp_off[j],  &kbuf[1][wave * 4096 + j * 1024]);

    for (int t = 0; t < 64; ++t) {
        if (t == 0)       { asm volatile("s_waitcnt vmcnt(4)"  ::: "memory"); }
        else if (t == 63) { asm volatile("s_waitcnt vmcnt(16)" ::: "memory"); }
        else              { asm volatile("s_waitcnt vmcnt(20)" ::: "memory"); }
        __builtin_amdgcn_sched_barrier(0);
        __builtin_amdgcn_s_barrier();
        __builtin_amdgcn_sched_barrier(0);

        // ---- QK(t) (LDS) || PV(t-1) (register-only, tt/pk from phase t-1, K=16 pairs) ----
        f32x4 s0 = zero, s1 = zero;
        const char* kb = kbuf[t % 3];
        __builtin_amdgcn_s_setprio(1);
#pragma unroll
        for (int ks = 0; ks < 8; ++ks) {
            bf16x8 k0 = *(const bf16x8*)(kb + (lo << 9) + ((ks * 64 + hi * 16) ^ kswz));
            bf16x8 k1 = *(const bf16x8*)(kb + ((16 + lo) << 9) + ((ks * 64 + hi * 16) ^ kswz));
            s0 = mfma16(k0, aq[ks], s0);
            s1 = mfma16(k1, aq[ks], s1);
        }
        if (t > 0) {
#pragma unroll
            for (int dt = 0; dt < 16; ++dt) {
                i32x4 w = __builtin_bit_cast(i32x4, tt[dt]);
                i32x2 wl = {w[0], w[1]}, wh = {w[2], w[3]};
                o[dt] = mfma1k(__builtin_bit_cast(s16x4, wl), pk0, o[dt]);
                o[dt] = mfma1k(__builtin_bit_cast(s16x4, wh), pk1, o[dt]);
            }
        }
        __builtin_amdgcn_s_setprio(0);

        // ---- reload tt(t) from L1 (PV consumed the old set); hides under softmax ----
        {
            const char* ttb = tsp_f + (long)t * 16384;
#pragma unroll
            for (int dt = 0; dt < 16; ++dt)
                tt[dt] = *(const bf16x8*)(ttb + dt * 1024);
        }
        // ---- DMA kp(t+2) into slot (t+2)%3 (read by all waves in phase t-1; barrier-safe) ----
        if (t < 62) {
            const char* src = kp_g + (long)(t + 2) * 16384;
            char* dst = &kbuf[(t + 2) % 3][wave * 4096];
#pragma unroll
            for (int j = 0; j < 4; ++j)
                load16_to_lds(src + kp_off[j], dst + j * 1024);
        }

        // ---- softmax(t): per-lane for q=lo (exp2 domain); pk = frag-ordered, no exchange ----
        float pm = fmaxf(fmaxf(fmaxf(s0[0], s0[1]), fmaxf(s0[2], s0[3])),
                         fmaxf(fmaxf(s1[0], s1[1]), fmaxf(s1[2], s1[3])));
        pm = fmaxf(pm, __shfl_xor(pm, 16));
        pm = fmaxf(pm, __shfl_xor(pm, 32));
        tm = fmaxf(tm, pm);
        if (__any(pm > m + 11.5f)) {      // defer-max: 8 nats = 11.5 bits
            float nm = fmaxf(m, pm);
            float a = exp2f(m - nm);
            m = nm;
            l *= a;
#pragma unroll
            for (int n = 0; n < 16; ++n) o[n] *= a;
        }
        float p0 = exp2f(s0[0] - m), p1 = exp2f(s0[1] - m);
        float p2 = exp2f(s0[2] - m), p3 = exp2f(s0[3] - m);
        float p4 = exp2f(s1[0] - m), p5 = exp2f(s1[1] - m);
        float p6 = exp2f(s1[2] - m), p7 = exp2f(s1[3] - m);
        l += (p0 + p1) + (p2 + p3) + (p4 + p5) + (p6 + p7);
        {
            bf16x4 a4, b4;
            a4[0] = (bf16)p0; a4[1] = (bf16)p1; a4[2] = (bf16)p2; a4[3] = (bf16)p3;
            b4[0] = (bf16)p4; b4[1] = (bf16)p5; b4[2] = (bf16)p6; b4[3] = (bf16)p7;
            pk0 = __builtin_bit_cast(s16x4, a4);   // kv = 4*hi + r      (S^T C row-map)
            pk1 = __builtin_bit_cast(s16x4, b4);   // kv = 16 + 4*hi + r
        }
    }

    // ---- tail: PV(63) ----
#pragma unroll
    for (int dt = 0; dt < 16; ++dt) {
        i32x4 w = __builtin_bit_cast(i32x4, tt[dt]);
        i32x2 wl = {w[0], w[1]}, wh = {w[2], w[3]};
        o[dt] = mfma1k(__builtin_bit_cast(s16x4, wl), pk0, o[dt]);
        o[dt] = mfma1k(__builtin_bit_cast(s16x4, wh), pk1, o[dt]);
    }

    // ---- epilogue: lane owns q-row lo; d = dt*16 + 4*hi + r ----
    l += __shfl_xor(l, 16);
    l += __shfl_xor(l, 32);
    float prob = 1.f / (1.f + __expf(-tm * 0.69314718f));
    float invl = 1.f / l;
    long row = qbase + wave * 16 + lo;
#pragma unroll
    for (int dt = 0; dt < 16; ++dt) {
        int c0 = dt * 16 + hi * 4;
        float4 qv = *(const float4*)(qorig + row * 256 + c0);
        bf16x4 g;
        g[0] = (bf16)((qv.x + o[dt][0] * invl) * prob);
        g[1] = (bf16)((qv.y + o[dt][1] * invl) * prob);
        g[2] = (bf16)((qv.z + o[dt][2] * invl) * prob);
        g[3] = (bf16)((qv.w + o[dt][3] * invl) * prob);
        *(bf16x4*)(gated + row * 256 + c0) = g;
    }
}

extern "C" void kernel_launch(void* const* d_in, const int* in_sizes, int n_in,
                              void* d_out, int out_size, void* d_ws, size_t ws_size,
                              hipStream_t stream) {
    const float* q    = (const float*)d_in[0];
    const float* k    = (const float*)d_in[1];
    const float* tsp  = (const float*)d_in[2];
    const float* w_qk = (const float*)d_in[3];
    const float* w1   = (const float*)d_in[4];
    const float* b1   = (const float*)d_in[5];
    float* out = (float*)d_out;
    char* ws = (char*)d_ws;

    bf16* qp_b  = (bf16*)(ws + 0);           // 16 MB
    bf16* kp_b  = (bf16*)(ws + 16777216);    // 16 MB
    bf16* tspF  = (bf16*)(ws + 33554432);    // 16 MB (K=16 frag layout)
    bf16* gated = (bf16*)(ws + 50331648);    // 16 MB

    prep_qk<<<3072, 256, 0, stream>>>(q, k, w_qk, tsp, qp_b, kp_b, tspF);

    flash13<<<512, 256, 0, stream>>>(qp_b, kp_b, tspF, q, gated);

    gemm_out<<<512, 256, 0, stream>>>(gated, w1, b1, out);
}